// Round 12
// baseline (726.584 us; speedup 1.0000x reference)
//
#include <hip/hip_runtime.h>
#include <hip/hip_fp16.h>

#define NN 100   // nodes
#define HH 32    // hidden
#define BB 8192  // batch
#define DD 32    // dags
#define TPB 1024 // 16 waves per block, 32 rows per wave

typedef _Float16 f16x8 __attribute__((ext_vector_type(8)));
typedef __fp16 fph2 __attribute__((ext_vector_type(2)));
typedef _Float16 f16x2 __attribute__((ext_vector_type(2)));
typedef float f32x4 __attribute__((ext_vector_type(4)));
typedef unsigned short ushort_t;
typedef unsigned int uint_t;
union FU { uint4 u; f16x8 h; };
union PU { fph2 p; f16x2 h; uint_t u; };

#define AS_GLOBAL __attribute__((address_space(1)))
#define AS_LDS    __attribute__((address_space(3)))

// LDS layout (bytes)
#define XS_OFF 65536
#define EPI4_OFF 73728
#define B2T_OFF 80128
#define INV_OFF 80528
#define SMEM_BYTES 80736

// ======================= prep =======================
// x (B,N) f32 -> xTh (N,B) fp16, per-32 pairing: rows (n16, n16+16) adjacent
__global__ void prep_xth(const float* __restrict__ x, ushort_t* __restrict__ xTh) {
  int idx = blockIdx.x * 256 + threadIdx.x;
  if (idx >= BB * NN) return;
  int b = idx & (BB - 1);
  int n = idx >> 13;
  int chunk = b >> 9;
  int r = b & 511;
  int wv = r >> 5, i = r & 31;
  int pp = wv * 32 + ((i & 15) << 1) + (i >> 4);
  xTh[(size_t)n * BB + chunk * 512 + pp] =
      __half_as_ushort(__float2half_rn(x[(size_t)b * NN + n]));
}

// W1P[d][node]: slice-major [s(4)][j(32)][k32(32)] fp16, octet-swizzled per row.
// slot 0 = b1; slot 1 = x-weight; slot >=2 = masked W1 for parent ord[d][slot-2].
__global__ void prep_w1p(const float* __restrict__ A, const float* __restrict__ W1,
                         const float* __restrict__ b1, const int* __restrict__ order,
                         ushort_t* __restrict__ W1P) {
  int idx = blockIdx.x * 256 + threadIdx.x;   // DD*NN*4096
  int tile = idx >> 12;
  int d = tile / NN;
  int node = tile - d * NN;
  int p = idx & 4095;
  int s = p >> 10;
  int j = (p >> 5) & 31;
  int w5 = p & 31;
  int o_sw = w5 >> 3;
  int e = w5 & 7;
  int kk = ((o_sw ^ (j & 3)) << 3) | e;
  int slot = (s << 5) | kk;
  float v = 0.f;
  if (slot == 0) {
    v = b1[node * HH + j];
  } else if (slot == 1) {
    v = W1[((size_t)node * HH + j) * (NN + 1) + NN];
  } else {
    int pos = slot - 2;
    if (pos < NN) {
      int parent = order[d * NN + pos];
      float m = A[((size_t)d * NN + parent) * NN + node];
      v = (m != 0.f) ? W1[((size_t)node * HH + j) * (NN + 1) + parent] : 0.f;
    }
  }
  W1P[idx] = __half_as_ushort(__float2half_rn(v));
}

// epi4[node][16 uints] W2 pairs laid for [g][r]; b2t[node]
__global__ void prep_epi4(const float* __restrict__ W2, const float* __restrict__ b2,
                          uint_t* __restrict__ epi4, float* __restrict__ b2t) {
  int idx = blockIdx.x * 256 + threadIdx.x;
  if (idx < NN * 16) {
    int node = idx >> 4;
    int g = (idx >> 2) & 3;
    int r = idx & 3;
    int j0 = ((r & 2) << 3) + 4 * g + ((r & 1) << 1);
    uint_t lo = __half_as_ushort(__float2half_rn(W2[node * HH + j0]));
    uint_t hi = __half_as_ushort(__float2half_rn(W2[node * HH + j0 + 1]));
    epi4[idx] = lo | (hi << 16);
  } else if (idx < NN * 16 + NN) {
    int node = idx - NN * 16;
    b2t[node] = b2[node];
  }
}

// ======================= 4-step body, NS compile-time =======================
template<int NS>
__device__ __forceinline__ void run4(
    const char* sp, uint4 (&breg)[2][4], const int* nd, const int di,
    const int tsb, const int xtb, const int vsw,
    const int w, const int n16, const int g, const int ss)
{
  const f32x4 zero4 = {0.f, 0.f, 0.f, 0.f};
  PU c001; c001.u = 0x211F211Fu;   // fp16 0.01 x2
#pragma unroll
  for (int q = 0; q < 4; ++q) {
    const int st = 4 * ss + q + 2;       // slot of this step's node
    const int node = nd[q];

    const uint_t xw = *(const uint_t*)(sp + XS_OFF + xtb + w * 64 + n16 * 4 + q * 1024);
    breg[0][0].x = (g == 0) ? (0x00003C00u | (xw << 16)) : breg[0][0].x;
    breg[1][0].x = (g == 0) ? (0x00003C00u | (xw & 0xFFFF0000u)) : breg[1][0].x;

    float val[2];
    if (node != di) {
      const uint4 w4 = *(const uint4*)(sp + EPI4_OFF + node * 64 + g * 16);
      const float b2n = *(const float*)(sp + B2T_OFF + node * 4);
      const int tb = tsb + q * 8192;
      f32x4 acc[2];
      float p0[2];

      // ---- phase 0: j = n16 rows
      __builtin_amdgcn_s_setprio(1);
#pragma unroll
      for (int s = 0; s < NS; ++s) {
        FU a, b0_, b1_;
        a.u = *(const uint4*)(sp + tb + s * 2048 + vsw);
        b0_.u = breg[0][s]; b1_.u = breg[1][s];
        if (s == 0) {
          acc[0] = __builtin_amdgcn_mfma_f32_16x16x32_f16(a.h, b0_.h, zero4, 0, 0, 0);
          acc[1] = __builtin_amdgcn_mfma_f32_16x16x32_f16(a.h, b1_.h, zero4, 0, 0, 0);
        } else {
          acc[0] = __builtin_amdgcn_mfma_f32_16x16x32_f16(a.h, b0_.h, acc[0], 0, 0, 0);
          acc[1] = __builtin_amdgcn_mfma_f32_16x16x32_f16(a.h, b1_.h, acc[1], 0, 0, 0);
        }
      }
      __builtin_amdgcn_s_setprio(0);
      {
        PU w01, w23; w01.u = w4.x; w23.u = w4.y;
#pragma unroll
        for (int nt = 0; nt < 2; ++nt) {
          PU h01, h23;
          h01.p = __builtin_amdgcn_cvt_pkrtz(acc[nt][0], acc[nt][1]);
          h23.p = __builtin_amdgcn_cvt_pkrtz(acc[nt][2], acc[nt][3]);
          h01.p = __builtin_elementwise_max(h01.p, h01.p * c001.p);
          h23.p = __builtin_elementwise_max(h23.p, h23.p * c001.p);
          float p = __builtin_amdgcn_fdot2(h01.h, w01.h, 0.f, false);
          p0[nt] = __builtin_amdgcn_fdot2(h23.h, w23.h, p, false);
        }
      }

      // ---- phase 1: j = 16 + n16 rows
      __builtin_amdgcn_s_setprio(1);
#pragma unroll
      for (int s = 0; s < NS; ++s) {
        FU a, b0_, b1_;
        a.u = *(const uint4*)(sp + tb + s * 2048 + 1024 + vsw);
        b0_.u = breg[0][s]; b1_.u = breg[1][s];
        if (s == 0) {
          acc[0] = __builtin_amdgcn_mfma_f32_16x16x32_f16(a.h, b0_.h, zero4, 0, 0, 0);
          acc[1] = __builtin_amdgcn_mfma_f32_16x16x32_f16(a.h, b1_.h, zero4, 0, 0, 0);
        } else {
          acc[0] = __builtin_amdgcn_mfma_f32_16x16x32_f16(a.h, b0_.h, acc[0], 0, 0, 0);
          acc[1] = __builtin_amdgcn_mfma_f32_16x16x32_f16(a.h, b1_.h, acc[1], 0, 0, 0);
        }
      }
      __builtin_amdgcn_s_setprio(0);
      {
        PU w45, w67; w45.u = w4.z; w67.u = w4.w;
#pragma unroll
        for (int nt = 0; nt < 2; ++nt) {
          PU h45, h67;
          h45.p = __builtin_amdgcn_cvt_pkrtz(acc[nt][0], acc[nt][1]);
          h67.p = __builtin_amdgcn_cvt_pkrtz(acc[nt][2], acc[nt][3]);
          h45.p = __builtin_elementwise_max(h45.p, h45.p * c001.p);
          h67.p = __builtin_elementwise_max(h67.p, h67.p * c001.p);
          float p = __builtin_amdgcn_fdot2(h45.h, w45.h, p0[nt], false);
          p = __builtin_amdgcn_fdot2(h67.h, w67.h, p, false);
          p += __shfl_xor(p, 16, 64);
          p += __shfl_xor(p, 32, 64);
          val[nt] = p + b2n;
        }
      }
    } else {
      val[0] = __half2float(__ushort_as_half((ushort_t)(xw & 0xFFFFu)));
      val[1] = __half2float(__ushort_as_half((ushort_t)(xw >> 16)));
    }

    // insert val (fp16) at slot st (wave-uniform selects; st < 32*NS guaranteed)
    const int sn = st >> 5;
    const int en2 = (st >> 1) & 3;
    const int gn = (st >> 3) & 3;
    const int hin = st & 1;
    const bool own = (g == gn);
    ushort_t hv[2];
    hv[0] = __half_as_ushort(__float2half_rn(val[0]));
    hv[1] = __half_as_ushort(__float2half_rn(val[1]));
#pragma unroll
    for (int S = 0; S < NS; ++S) {
      if (S != sn) continue;    // uniform
#pragma unroll
      for (int nt = 0; nt < 2; ++nt) {
        uint4& Bq = breg[nt][S];
        uint_t hvn = (uint_t)hv[nt];
        if (en2 == 0) {
          uint_t old = Bq.x;
          uint_t nw = hin ? ((old & 0x0000FFFFu) | (hvn << 16)) : ((old & 0xFFFF0000u) | hvn);
          Bq.x = own ? nw : old;
        } else if (en2 == 1) {
          uint_t old = Bq.y;
          uint_t nw = hin ? ((old & 0x0000FFFFu) | (hvn << 16)) : ((old & 0xFFFF0000u) | hvn);
          Bq.y = own ? nw : old;
        } else if (en2 == 2) {
          uint_t old = Bq.z;
          uint_t nw = hin ? ((old & 0x0000FFFFu) | (hvn << 16)) : ((old & 0xFFFF0000u) | hvn);
          Bq.z = own ? nw : old;
        } else {
          uint_t old = Bq.w;
          uint_t nw = hin ? ((old & 0x0000FFFFu) | (hvn << 16)) : ((old & 0xFFFF0000u) | hvn);
          Bq.w = own ? nw : old;
        }
      }
    }
  }
}

// ======================= main =======================
__global__ __launch_bounds__(TPB, 8) void dag_mfma_ks(
    const ushort_t* __restrict__ xTh,  // [N][B] fp16 paired
    const int* __restrict__ order,     // [D][N]
    const int* __restrict__ do_idx_p,  // [1]
    const ushort_t* __restrict__ W1P,  // [D][N][4096] fp16 slice-major swizzled
    const uint_t* __restrict__ epi4_g, // [N][16]
    const float* __restrict__ b2t_g,   // [N]
    float* __restrict__ out)           // [D][B][N]
{
  __shared__ __align__(16) char smem[SMEM_BYTES];
  const char* sp = (const char*)smem;

  const int d = blockIdx.y;
  const int bx = blockIdx.x;
  const int tid = threadIdx.x;
  const int w = tid >> 6;
  const int lane = tid & 63;
  const int g = lane >> 4;
  const int n16 = lane & 15;
  const int di = __builtin_amdgcn_readfirstlane(do_idx_p[0]);
  const int* ord = order + d * NN;

  // preloads: epi4 (400 uint4), b2t (100 f32), inv table (100 u16)
  {
    const uint4* s4 = (const uint4*)epi4_g;
    uint4* d4 = (uint4*)(smem + EPI4_OFF);
    for (int i = tid; i < 400; i += TPB) d4[i] = s4[i];
    if (tid < NN) {
      ((float*)(smem + B2T_OFF))[tid] = b2t_g[tid];
      ((ushort_t*)(smem + INV_OFF))[ord[tid]] = (ushort_t)(tid + 2);
    }
  }

  const ushort_t* Wd = W1P + (size_t)d * NN * 4096;
  const int vsw = n16 * 64 + ((g ^ (n16 & 3)) << 4);
  int tsb = 32768;
  int xtb = 4096;

  int nd[4], nn2[4];
#pragma unroll
  for (int q = 0; q < 4; ++q) { nd[q] = __builtin_amdgcn_readfirstlane(ord[q]); nn2[q] = nd[q]; }
  {
    const int q = w >> 2, c = w & 3;   // ss=0: NS=1 -> 2 chunks
    const char* gb = (const char*)Wd + (size_t)nd[q] * 8192;
    if (c < 2) {
      __builtin_amdgcn_global_load_lds(
          (const AS_GLOBAL void*)(gb + c * 1024 + (size_t)lane * 16),
          (AS_LDS void*)(smem + q * 8192 + c * 1024), 16, 0, 0);
    }
  }
#pragma unroll
  for (int q = 0; q < 4; ++q) {
    if (w == q) {
      const ushort_t* gx = xTh + (size_t)nd[q] * BB + bx * 512 + lane * 8;
      __builtin_amdgcn_global_load_lds((const AS_GLOBAL void*)gx,
          (AS_LDS void*)(smem + XS_OFF + q * 1024), 16, 0, 0);
    }
  }

  uint4 breg[2][4];
#pragma unroll
  for (int nt = 0; nt < 2; ++nt) {
#pragma unroll
    for (int S = 0; S < 4; ++S) breg[nt][S] = make_uint4(0u, 0u, 0u, 0u);
    breg[nt][0].x = (g == 0) ? 0x00003C00u : 0u;
  }

#pragma unroll 1
  for (int ss = 0; ss < 25; ++ss) {
    asm volatile("s_waitcnt vmcnt(0) lgkmcnt(0)" ::: "memory");
    __builtin_amdgcn_s_barrier();
    __builtin_amdgcn_sched_barrier(0);

    tsb ^= 32768;
    xtb ^= 4096;

    const bool more = (ss < 24);
    if (more) {
#pragma unroll
      for (int q = 0; q < 4; ++q)
        nn2[q] = __builtin_amdgcn_readfirstlane(ord[4 * (ss + 1) + q]);
      const int nC = ((4 * ss + 41) >> 5) << 1;   // chunks = 2*NS(ss+1)
      const int dset = tsb ^ 32768;
      {
        const int q = w >> 2, c = w & 3;
        const char* gb = (const char*)Wd + (size_t)nn2[q] * 8192;
        char* lb = (char*)smem + dset + q * 8192;
        if (c < nC) {
          __builtin_amdgcn_global_load_lds(
              (const AS_GLOBAL void*)(gb + c * 1024 + (size_t)lane * 16),
              (AS_LDS void*)(lb + c * 1024), 16, 0, 0);
        }
        if (c + 4 < nC) {
          __builtin_amdgcn_global_load_lds(
              (const AS_GLOBAL void*)(gb + (c + 4) * 1024 + (size_t)lane * 16),
              (AS_LDS void*)(lb + (c + 4) * 1024), 16, 0, 0);
        }
      }
      const int xd = XS_OFF + (xtb ^ 4096);
#pragma unroll
      for (int q = 0; q < 4; ++q) {
        if (w == q) {
          const ushort_t* gx = xTh + (size_t)nn2[q] * BB + bx * 512 + lane * 8;
          __builtin_amdgcn_global_load_lds((const AS_GLOBAL void*)gx,
              (AS_LDS void*)(smem + xd + q * 1024), 16, 0, 0);
        }
      }
    }

    // block-uniform dispatch on compile-time slice count
    const int nSc = (4 * ss + 37) >> 5;
    switch (nSc) {
      case 1: run4<1>(sp, breg, nd, di, tsb, xtb, vsw, w, n16, g, ss); break;
      case 2: run4<2>(sp, breg, nd, di, tsb, xtb, vsw, w, n16, g, ss); break;
      case 3: run4<3>(sp, breg, nd, di, tsb, xtb, vsw, w, n16, g, ss); break;
      default: run4<4>(sp, breg, nd, di, tsb, xtb, vsw, w, n16, g, ss); break;
    }

#pragma unroll
    for (int q = 0; q < 4; ++q) nd[q] = nn2[q];
  }

  // ---- output: per-wave 32-row LDS transpose chunks; inv maps node->slot
  ushort_t* tbuf = (ushort_t*)smem;   // 32*132 halfs
  const ushort_t* invp = (const ushort_t*)(smem + INV_OFF);
#pragma unroll 1
  for (int c = 0; c < 16; ++c) {
    __syncthreads();
    if (w == c) {
#pragma unroll
      for (int nt = 0; nt < 2; ++nt) {
        int r = nt * 16 + n16;
#pragma unroll
        for (int S = 0; S < 4; ++S) {
          int k = 32 * S + 8 * g;
          *(uint2*)&tbuf[r * 132 + k] = make_uint2(breg[nt][S].x, breg[nt][S].y);
          *(uint2*)&tbuf[r * 132 + k + 4] = make_uint2(breg[nt][S].z, breg[nt][S].w);
        }
      }
    }
    __syncthreads();
    const size_t obase = ((size_t)d * BB + bx * 512 + c * 32) * NN;
    for (int idx = tid; idx < 32 * NN; idx += TPB) {
      int rl = idx / NN;
      int col = idx - rl * NN;
      int slot = invp[col];
      out[obase + idx] = __half2float(__ushort_as_half(tbuf[rl * 132 + slot]));
    }
  }
}

// ======================= launch =======================
extern "C" void kernel_launch(void* const* d_in, const int* in_sizes, int n_in,
                              void* d_out, int out_size, void* d_ws, size_t ws_size,
                              hipStream_t stream) {
  const float* x     = (const float*)d_in[0];
  const float* A     = (const float*)d_in[1];
  const int* order   = (const int*)d_in[2];
  const int* do_idx  = (const int*)d_in[3];
  const float* W1    = (const float*)d_in[4];
  const float* b1    = (const float*)d_in[5];
  const float* W2    = (const float*)d_in[6];
  const float* b2    = (const float*)d_in[7];
  float* out = (float*)d_out;

  char* ws = (char*)d_ws;
  const size_t XTH_B = (size_t)BB * NN * 2;         // 1,638,400
  const size_t W1P_B = (size_t)DD * NN * 4096 * 2;  // 26,214,400
  ushort_t* xTh  = (ushort_t*)ws;
  ushort_t* W1P  = (ushort_t*)(ws + XTH_B);
  uint_t* epi4   = (uint_t*)(ws + XTH_B + W1P_B);           // 6,400 B
  float* b2t     = (float*)(ws + XTH_B + W1P_B + 6400);     // 400 B

  hipLaunchKernelGGL(prep_xth, dim3((BB * NN) / 256), dim3(256), 0, stream, x, xTh);
  hipLaunchKernelGGL(prep_w1p, dim3((DD * NN * 4096) / 256), dim3(256), 0, stream,
                     A, W1, b1, order, W1P);
  hipLaunchKernelGGL(prep_epi4, dim3((NN * 16 + NN + 255) / 256), dim3(256), 0, stream,
                     W2, b2, epi4, b2t);
  hipLaunchKernelGGL(dag_mfma_ks, dim3(BB / 512, DD), dim3(TPB), 0, stream,
                     xTh, order, do_idx, W1P, epi4, b2t, out);
}

// Round 13
// 287.816 us; speedup vs baseline: 2.5245x; 2.5245x over previous
//
#include <hip/hip_runtime.h>
#include <hip/hip_fp16.h>

#define NN 100   // nodes
#define HH 32    // hidden
#define BB 8192  // batch
#define DD 32    // dags
#define TPB 1024 // 16 waves per block, 32 rows per wave

typedef _Float16 f16x8 __attribute__((ext_vector_type(8)));
typedef __fp16 fph2 __attribute__((ext_vector_type(2)));
typedef _Float16 f16x2 __attribute__((ext_vector_type(2)));
typedef float f32x4 __attribute__((ext_vector_type(4)));
typedef unsigned short ushort_t;
typedef unsigned int uint_t;
union FU { uint4 u; f16x8 h; };
union PU { fph2 p; f16x2 h; uint_t u; };

#define AS_GLOBAL __attribute__((address_space(1)))
#define AS_LDS    __attribute__((address_space(3)))

// LDS layout (bytes)
#define XS_OFF 65536
#define EPI4_OFF 73728
#define B2T_OFF 80128
#define INV_OFF 80528
#define SMEM_BYTES 80736

// ======================= prep =======================
// x (B,N) f32 -> xTh (N,B) fp16, per-32 pairing: rows (n16, n16+16) adjacent
__global__ void prep_xth(const float* __restrict__ x, ushort_t* __restrict__ xTh) {
  int idx = blockIdx.x * 256 + threadIdx.x;
  if (idx >= BB * NN) return;
  int b = idx & (BB - 1);
  int n = idx >> 13;
  int chunk = b >> 9;
  int r = b & 511;
  int wv = r >> 5, i = r & 31;
  int pp = wv * 32 + ((i & 15) << 1) + (i >> 4);
  xTh[(size_t)n * BB + chunk * 512 + pp] =
      __half_as_ushort(__float2half_rn(x[(size_t)b * NN + n]));
}

// W1P[d][node]: slice-major [s(4)][j(32)][k32(32)] fp16, octet-swizzled per row.
// slot 0 = b1; slot 1 = x-weight; slot >=2 = masked W1 for parent ord[d][slot-2].
__global__ void prep_w1p(const float* __restrict__ A, const float* __restrict__ W1,
                         const float* __restrict__ b1, const int* __restrict__ order,
                         ushort_t* __restrict__ W1P) {
  int idx = blockIdx.x * 256 + threadIdx.x;   // DD*NN*4096
  int tile = idx >> 12;
  int d = tile / NN;
  int node = tile - d * NN;
  int p = idx & 4095;
  int s = p >> 10;
  int j = (p >> 5) & 31;
  int w5 = p & 31;
  int o_sw = w5 >> 3;
  int e = w5 & 7;
  int kk = ((o_sw ^ (j & 3)) << 3) | e;
  int slot = (s << 5) | kk;
  float v = 0.f;
  if (slot == 0) {
    v = b1[node * HH + j];
  } else if (slot == 1) {
    v = W1[((size_t)node * HH + j) * (NN + 1) + NN];
  } else {
    int pos = slot - 2;
    if (pos < NN) {
      int parent = order[d * NN + pos];
      float m = A[((size_t)d * NN + parent) * NN + node];
      v = (m != 0.f) ? W1[((size_t)node * HH + j) * (NN + 1) + parent] : 0.f;
    }
  }
  W1P[idx] = __half_as_ushort(__float2half_rn(v));
}

// epi4[node][16 uints] W2 pairs laid for [g][r]; b2t[node]
__global__ void prep_epi4(const float* __restrict__ W2, const float* __restrict__ b2,
                          uint_t* __restrict__ epi4, float* __restrict__ b2t) {
  int idx = blockIdx.x * 256 + threadIdx.x;
  if (idx < NN * 16) {
    int node = idx >> 4;
    int g = (idx >> 2) & 3;
    int r = idx & 3;
    int j0 = ((r & 2) << 3) + 4 * g + ((r & 1) << 1);
    uint_t lo = __half_as_ushort(__float2half_rn(W2[node * HH + j0]));
    uint_t hi = __half_as_ushort(__float2half_rn(W2[node * HH + j0 + 1]));
    epi4[idx] = lo | (hi << 16);
  } else if (idx < NN * 16 + NN) {
    int node = idx - NN * 16;
    b2t[node] = b2[node];
  }
}

// ======================= superstep macro (textual, allocator-safe) ==========
#define SUPERSTEP_BODY(NSC)                                                    \
  {                                                                            \
    asm volatile("s_waitcnt vmcnt(0) lgkmcnt(0)" ::: "memory");                \
    __builtin_amdgcn_s_barrier();                                              \
    __builtin_amdgcn_sched_barrier(0);                                         \
    tsb ^= 32768;                                                              \
    xtb ^= 4096;                                                               \
    if (ss < 24) {                                                             \
      _Pragma("unroll")                                                        \
      for (int q = 0; q < 4; ++q)                                              \
        nn2[q] = __builtin_amdgcn_readfirstlane(ord[4 * (ss + 1) + q]);        \
      const int nC = ((4 * ss + 41) >> 5) << 1;                                \
      const int dset = tsb ^ 32768;                                            \
      {                                                                        \
        const int q2 = w >> 2, c2 = w & 3;                                     \
        const char* gb = (const char*)Wd + (size_t)nn2[q2] * 8192;             \
        char* lb = (char*)smem + dset + q2 * 8192;                             \
        if (c2 < nC) {                                                         \
          __builtin_amdgcn_global_load_lds(                                    \
              (const AS_GLOBAL void*)(gb + c2 * 1024 + (size_t)lane * 16),     \
              (AS_LDS void*)(lb + c2 * 1024), 16, 0, 0);                       \
        }                                                                      \
        if (c2 + 4 < nC) {                                                     \
          __builtin_amdgcn_global_load_lds(                                    \
              (const AS_GLOBAL void*)(gb + (c2 + 4) * 1024 + (size_t)lane * 16), \
              (AS_LDS void*)(lb + (c2 + 4) * 1024), 16, 0, 0);                 \
        }                                                                      \
      }                                                                        \
      const int xd = XS_OFF + (xtb ^ 4096);                                    \
      _Pragma("unroll")                                                        \
      for (int q = 0; q < 4; ++q) {                                            \
        if (w == q) {                                                          \
          const ushort_t* gx = xTh + (size_t)nn2[q] * BB + bx * 512 + lane * 8;\
          __builtin_amdgcn_global_load_lds((const AS_GLOBAL void*)gx,          \
              (AS_LDS void*)(smem + xd + q * 1024), 16, 0, 0);                 \
        }                                                                      \
      }                                                                        \
    }                                                                          \
    _Pragma("unroll")                                                          \
    for (int q = 0; q < 4; ++q) {                                              \
      const int st = 4 * ss + q + 2;                                           \
      const int node = nd[q];                                                  \
      const uint_t xw =                                                        \
          *(const uint_t*)(sp + XS_OFF + xtb + w * 64 + n16 * 4 + q * 1024);   \
      breg[0][0].x = (g == 0) ? (0x00003C00u | (xw << 16)) : breg[0][0].x;     \
      breg[1][0].x = (g == 0) ? (0x00003C00u | (xw & 0xFFFF0000u)) : breg[1][0].x; \
      float val0, val1;                                                        \
      if (node != di) {                                                        \
        const uint4 w4 = *(const uint4*)(sp + EPI4_OFF + node * 64 + g * 16);  \
        const float b2n = *(const float*)(sp + B2T_OFF + node * 4);            \
        const int tb = tsb + q * 8192;                                         \
        f32x4 acc0, acc1;                                                      \
        float p00, p01;                                                        \
        __builtin_amdgcn_s_setprio(1);                                         \
        _Pragma("unroll")                                                      \
        for (int s = 0; s < (NSC); ++s) {                                      \
          FU a, b0_, b1_;                                                      \
          a.u = *(const uint4*)(sp + tb + s * 2048 + vsw);                     \
          b0_.u = breg[0][s]; b1_.u = breg[1][s];                              \
          if (s == 0) {                                                        \
            acc0 = __builtin_amdgcn_mfma_f32_16x16x32_f16(a.h, b0_.h, zero4, 0, 0, 0); \
            acc1 = __builtin_amdgcn_mfma_f32_16x16x32_f16(a.h, b1_.h, zero4, 0, 0, 0); \
          } else {                                                             \
            acc0 = __builtin_amdgcn_mfma_f32_16x16x32_f16(a.h, b0_.h, acc0, 0, 0, 0); \
            acc1 = __builtin_amdgcn_mfma_f32_16x16x32_f16(a.h, b1_.h, acc1, 0, 0, 0); \
          }                                                                    \
        }                                                                      \
        __builtin_amdgcn_s_setprio(0);                                         \
        {                                                                      \
          PU w01, w23; w01.u = w4.x; w23.u = w4.y;                             \
          PU h01, h23;                                                         \
          h01.p = __builtin_amdgcn_cvt_pkrtz(acc0[0], acc0[1]);                \
          h23.p = __builtin_amdgcn_cvt_pkrtz(acc0[2], acc0[3]);                \
          h01.p = __builtin_elementwise_max(h01.p, h01.p * c001.p);            \
          h23.p = __builtin_elementwise_max(h23.p, h23.p * c001.p);            \
          float p = __builtin_amdgcn_fdot2(h01.h, w01.h, 0.f, false);          \
          p00 = __builtin_amdgcn_fdot2(h23.h, w23.h, p, false);                \
          h01.p = __builtin_amdgcn_cvt_pkrtz(acc1[0], acc1[1]);                \
          h23.p = __builtin_amdgcn_cvt_pkrtz(acc1[2], acc1[3]);                \
          h01.p = __builtin_elementwise_max(h01.p, h01.p * c001.p);            \
          h23.p = __builtin_elementwise_max(h23.p, h23.p * c001.p);            \
          p = __builtin_amdgcn_fdot2(h01.h, w01.h, 0.f, false);                \
          p01 = __builtin_amdgcn_fdot2(h23.h, w23.h, p, false);                \
        }                                                                      \
        __builtin_amdgcn_s_setprio(1);                                         \
        _Pragma("unroll")                                                      \
        for (int s = 0; s < (NSC); ++s) {                                      \
          FU a, b0_, b1_;                                                      \
          a.u = *(const uint4*)(sp + tb + s * 2048 + 1024 + vsw);              \
          b0_.u = breg[0][s]; b1_.u = breg[1][s];                              \
          if (s == 0) {                                                        \
            acc0 = __builtin_amdgcn_mfma_f32_16x16x32_f16(a.h, b0_.h, zero4, 0, 0, 0); \
            acc1 = __builtin_amdgcn_mfma_f32_16x16x32_f16(a.h, b1_.h, zero4, 0, 0, 0); \
          } else {                                                             \
            acc0 = __builtin_amdgcn_mfma_f32_16x16x32_f16(a.h, b0_.h, acc0, 0, 0, 0); \
            acc1 = __builtin_amdgcn_mfma_f32_16x16x32_f16(a.h, b1_.h, acc1, 0, 0, 0); \
          }                                                                    \
        }                                                                      \
        __builtin_amdgcn_s_setprio(0);                                         \
        {                                                                      \
          PU w45, w67; w45.u = w4.z; w67.u = w4.w;                             \
          PU h45, h67;                                                         \
          h45.p = __builtin_amdgcn_cvt_pkrtz(acc0[0], acc0[1]);                \
          h67.p = __builtin_amdgcn_cvt_pkrtz(acc0[2], acc0[3]);                \
          h45.p = __builtin_elementwise_max(h45.p, h45.p * c001.p);            \
          h67.p = __builtin_elementwise_max(h67.p, h67.p * c001.p);            \
          float p = __builtin_amdgcn_fdot2(h45.h, w45.h, p00, false);          \
          p = __builtin_amdgcn_fdot2(h67.h, w67.h, p, false);                  \
          p += __shfl_xor(p, 16, 64);                                          \
          p += __shfl_xor(p, 32, 64);                                          \
          val0 = p + b2n;                                                      \
          h45.p = __builtin_amdgcn_cvt_pkrtz(acc1[0], acc1[1]);                \
          h67.p = __builtin_amdgcn_cvt_pkrtz(acc1[2], acc1[3]);                \
          h45.p = __builtin_elementwise_max(h45.p, h45.p * c001.p);            \
          h67.p = __builtin_elementwise_max(h67.p, h67.p * c001.p);            \
          p = __builtin_amdgcn_fdot2(h45.h, w45.h, p01, false);                \
          p = __builtin_amdgcn_fdot2(h67.h, w67.h, p, false);                  \
          p += __shfl_xor(p, 16, 64);                                          \
          p += __shfl_xor(p, 32, 64);                                          \
          val1 = p + b2n;                                                      \
        }                                                                      \
      } else {                                                                 \
        val0 = __half2float(__ushort_as_half((ushort_t)(xw & 0xFFFFu)));       \
        val1 = __half2float(__ushort_as_half((ushort_t)(xw >> 16)));           \
      }                                                                        \
      const int sn = st >> 5;                                                  \
      const int en2 = (st >> 1) & 3;                                           \
      const int gn = (st >> 3) & 3;                                            \
      const int hin = st & 1;                                                  \
      const bool own = (g == gn);                                              \
      const uint_t hv0 = (uint_t)__half_as_ushort(__float2half_rn(val0));      \
      const uint_t hv1 = (uint_t)__half_as_ushort(__float2half_rn(val1));      \
      _Pragma("unroll")                                                        \
      for (int S = 0; S < (NSC); ++S) {                                        \
        if (S != sn) continue;                                                 \
        _Pragma("unroll")                                                      \
        for (int nt = 0; nt < 2; ++nt) {                                       \
          uint4& Bq = breg[nt][S];                                             \
          uint_t hvn = nt ? hv1 : hv0;                                         \
          if (en2 == 0) {                                                      \
            uint_t old = Bq.x;                                                 \
            uint_t nw = hin ? ((old & 0x0000FFFFu) | (hvn << 16))              \
                            : ((old & 0xFFFF0000u) | hvn);                     \
            Bq.x = own ? nw : old;                                             \
          } else if (en2 == 1) {                                               \
            uint_t old = Bq.y;                                                 \
            uint_t nw = hin ? ((old & 0x0000FFFFu) | (hvn << 16))              \
                            : ((old & 0xFFFF0000u) | hvn);                     \
            Bq.y = own ? nw : old;                                             \
          } else if (en2 == 2) {                                               \
            uint_t old = Bq.z;                                                 \
            uint_t nw = hin ? ((old & 0x0000FFFFu) | (hvn << 16))              \
                            : ((old & 0xFFFF0000u) | hvn);                     \
            Bq.z = own ? nw : old;                                             \
          } else {                                                             \
            uint_t old = Bq.w;                                                 \
            uint_t nw = hin ? ((old & 0x0000FFFFu) | (hvn << 16))              \
                            : ((old & 0xFFFF0000u) | hvn);                     \
            Bq.w = own ? nw : old;                                             \
          }                                                                    \
        }                                                                      \
      }                                                                        \
    }                                                                          \
    _Pragma("unroll")                                                          \
    for (int q = 0; q < 4; ++q) nd[q] = nn2[q];                                \
  }

// ======================= main =======================
__global__ __launch_bounds__(TPB, 8) void dag_mfma_ks(
    const ushort_t* __restrict__ xTh,  // [N][B] fp16 paired
    const int* __restrict__ order,     // [D][N]
    const int* __restrict__ do_idx_p,  // [1]
    const ushort_t* __restrict__ W1P,  // [D][N][4096] fp16 slice-major swizzled
    const uint_t* __restrict__ epi4_g, // [N][16]
    const float* __restrict__ b2t_g,   // [N]
    float* __restrict__ out)           // [D][B][N]
{
  __shared__ __align__(16) char smem[SMEM_BYTES];
  const char* sp = (const char*)smem;

  const int d = blockIdx.y;
  const int bx = blockIdx.x;
  const int tid = threadIdx.x;
  const int w = tid >> 6;
  const int lane = tid & 63;
  const int g = lane >> 4;
  const int n16 = lane & 15;
  const int di = __builtin_amdgcn_readfirstlane(do_idx_p[0]);
  const int* ord = order + d * NN;

  // preloads: epi4 (400 uint4), b2t (100 f32), inv table (100 u16)
  {
    const uint4* s4 = (const uint4*)epi4_g;
    uint4* d4 = (uint4*)(smem + EPI4_OFF);
    for (int i = tid; i < 400; i += TPB) d4[i] = s4[i];
    if (tid < NN) {
      ((float*)(smem + B2T_OFF))[tid] = b2t_g[tid];
      ((ushort_t*)(smem + INV_OFF))[ord[tid]] = (ushort_t)(tid + 2);
    }
  }

  const ushort_t* Wd = W1P + (size_t)d * NN * 4096;
  const int vsw = n16 * 64 + ((g ^ (n16 & 3)) << 4);
  int tsb = 32768;
  int xtb = 4096;

  int nd[4], nn2[4];
#pragma unroll
  for (int q = 0; q < 4; ++q) { nd[q] = __builtin_amdgcn_readfirstlane(ord[q]); nn2[q] = nd[q]; }
  {
    const int q = w >> 2, c = w & 3;   // ss=0: NS=1 -> 2 chunks
    const char* gb = (const char*)Wd + (size_t)nd[q] * 8192;
    if (c < 2) {
      __builtin_amdgcn_global_load_lds(
          (const AS_GLOBAL void*)(gb + c * 1024 + (size_t)lane * 16),
          (AS_LDS void*)(smem + q * 8192 + c * 1024), 16, 0, 0);
    }
  }
#pragma unroll
  for (int q = 0; q < 4; ++q) {
    if (w == q) {
      const ushort_t* gx = xTh + (size_t)nd[q] * BB + bx * 512 + lane * 8;
      __builtin_amdgcn_global_load_lds((const AS_GLOBAL void*)gx,
          (AS_LDS void*)(smem + XS_OFF + q * 1024), 16, 0, 0);
    }
  }

  uint4 breg[2][4];
#pragma unroll
  for (int nt = 0; nt < 2; ++nt) {
#pragma unroll
    for (int S = 0; S < 4; ++S) breg[nt][S] = make_uint4(0u, 0u, 0u, 0u);
    breg[nt][0].x = (g == 0) ? 0x00003C00u : 0u;
  }

  const f32x4 zero4 = {0.f, 0.f, 0.f, 0.f};
  PU c001; c001.u = 0x211F211Fu;   // fp16 0.01 x2

  // four sequential loops, NS compile-time per loop (monotone schedule)
#pragma unroll 1
  for (int ss = 0; ss < 7; ++ss) SUPERSTEP_BODY(1)
#pragma unroll 1
  for (int ss = 7; ss < 15; ++ss) SUPERSTEP_BODY(2)
#pragma unroll 1
  for (int ss = 15; ss < 23; ++ss) SUPERSTEP_BODY(3)
#pragma unroll 1
  for (int ss = 23; ss < 25; ++ss) SUPERSTEP_BODY(4)

  // ---- output: per-wave 32-row LDS transpose chunks; inv maps node->slot
  ushort_t* tbuf = (ushort_t*)smem;   // 32*132 halfs
  const ushort_t* invp = (const ushort_t*)(smem + INV_OFF);
#pragma unroll 1
  for (int c = 0; c < 16; ++c) {
    __syncthreads();
    if (w == c) {
#pragma unroll
      for (int nt = 0; nt < 2; ++nt) {
        int r = nt * 16 + n16;
#pragma unroll
        for (int S = 0; S < 4; ++S) {
          int k = 32 * S + 8 * g;
          *(uint2*)&tbuf[r * 132 + k] = make_uint2(breg[nt][S].x, breg[nt][S].y);
          *(uint2*)&tbuf[r * 132 + k + 4] = make_uint2(breg[nt][S].z, breg[nt][S].w);
        }
      }
    }
    __syncthreads();
    const size_t obase = ((size_t)d * BB + bx * 512 + c * 32) * NN;
    for (int idx = tid; idx < 32 * NN; idx += TPB) {
      int rl = idx / NN;
      int col = idx - rl * NN;
      int slot = invp[col];
      out[obase + idx] = __half2float(__ushort_as_half(tbuf[rl * 132 + slot]));
    }
  }
}

// ======================= launch =======================
extern "C" void kernel_launch(void* const* d_in, const int* in_sizes, int n_in,
                              void* d_out, int out_size, void* d_ws, size_t ws_size,
                              hipStream_t stream) {
  const float* x     = (const float*)d_in[0];
  const float* A     = (const float*)d_in[1];
  const int* order   = (const int*)d_in[2];
  const int* do_idx  = (const int*)d_in[3];
  const float* W1    = (const float*)d_in[4];
  const float* b1    = (const float*)d_in[5];
  const float* W2    = (const float*)d_in[6];
  const float* b2    = (const float*)d_in[7];
  float* out = (float*)d_out;

  char* ws = (char*)d_ws;
  const size_t XTH_B = (size_t)BB * NN * 2;         // 1,638,400
  const size_t W1P_B = (size_t)DD * NN * 4096 * 2;  // 26,214,400
  ushort_t* xTh  = (ushort_t*)ws;
  ushort_t* W1P  = (ushort_t*)(ws + XTH_B);
  uint_t* epi4   = (uint_t*)(ws + XTH_B + W1P_B);           // 6,400 B
  float* b2t     = (float*)(ws + XTH_B + W1P_B + 6400);     // 400 B

  hipLaunchKernelGGL(prep_xth, dim3((BB * NN) / 256), dim3(256), 0, stream, x, xTh);
  hipLaunchKernelGGL(prep_w1p, dim3((DD * NN * 4096) / 256), dim3(256), 0, stream,
                     A, W1, b1, order, W1P);
  hipLaunchKernelGGL(prep_epi4, dim3((NN * 16 + NN + 255) / 256), dim3(256), 0, stream,
                     W2, b2, epi4, b2t);
  hipLaunchKernelGGL(dag_mfma_ks, dim3(BB / 512, DD), dim3(TPB), 0, stream,
                     xTh, order, do_idx, W1P, epi4, b2t, out);
}

// Round 14
// 272.336 us; speedup vs baseline: 2.6680x; 1.0568x over previous
//
#include <hip/hip_runtime.h>
#include <hip/hip_fp16.h>

#define NN 100   // nodes
#define HH 32    // hidden
#define BB 8192  // batch
#define DD 32    // dags
#define TPB 1024 // 16 waves per block, 32 rows per wave

typedef _Float16 f16x8 __attribute__((ext_vector_type(8)));
typedef __fp16 fph2 __attribute__((ext_vector_type(2)));
typedef _Float16 f16x2 __attribute__((ext_vector_type(2)));
typedef float f32x4 __attribute__((ext_vector_type(4)));
typedef unsigned short ushort_t;
typedef unsigned int uint_t;
union FU { uint4 u; f16x8 h; };
union PU { fph2 p; f16x2 h; uint_t u; };

#define AS_GLOBAL __attribute__((address_space(1)))
#define AS_LDS    __attribute__((address_space(3)))

// static-index select from a 4-elem array (avoids scratch demotion, rule #20)
#define SELQ(arr, qq) ((qq) == 0 ? arr[0] : (qq) == 1 ? arr[1] : (qq) == 2 ? arr[2] : arr[3])

// LDS layout (bytes)
#define XS_OFF 65536
#define EPI4_OFF 73728
#define B2T_OFF 80128
#define INV_OFF 80528
#define SMEM_BYTES 80736

// ======================= prep =======================
// x (B,N) f32 -> xTh (N,B) fp16, per-32 pairing: rows (n16, n16+16) adjacent
__global__ void prep_xth(const float* __restrict__ x, ushort_t* __restrict__ xTh) {
  int idx = blockIdx.x * 256 + threadIdx.x;
  if (idx >= BB * NN) return;
  int b = idx & (BB - 1);
  int n = idx >> 13;
  int chunk = b >> 9;
  int r = b & 511;
  int wv = r >> 5, i = r & 31;
  int pp = wv * 32 + ((i & 15) << 1) + (i >> 4);
  xTh[(size_t)n * BB + chunk * 512 + pp] =
      __half_as_ushort(__float2half_rn(x[(size_t)b * NN + n]));
}

// W1P[d][node]: slice-major [s(4)][j(32)][k32(32)] fp16, octet-swizzled per row.
// slot 0 = b1; slot 1 = x-weight; slot >=2 = masked W1 for parent ord[d][slot-2].
__global__ void prep_w1p(const float* __restrict__ A, const float* __restrict__ W1,
                         const float* __restrict__ b1, const int* __restrict__ order,
                         ushort_t* __restrict__ W1P) {
  int idx = blockIdx.x * 256 + threadIdx.x;   // DD*NN*4096
  int tile = idx >> 12;
  int d = tile / NN;
  int node = tile - d * NN;
  int p = idx & 4095;
  int s = p >> 10;
  int j = (p >> 5) & 31;
  int w5 = p & 31;
  int o_sw = w5 >> 3;
  int e = w5 & 7;
  int kk = ((o_sw ^ (j & 3)) << 3) | e;
  int slot = (s << 5) | kk;
  float v = 0.f;
  if (slot == 0) {
    v = b1[node * HH + j];
  } else if (slot == 1) {
    v = W1[((size_t)node * HH + j) * (NN + 1) + NN];
  } else {
    int pos = slot - 2;
    if (pos < NN) {
      int parent = order[d * NN + pos];
      float m = A[((size_t)d * NN + parent) * NN + node];
      v = (m != 0.f) ? W1[((size_t)node * HH + j) * (NN + 1) + parent] : 0.f;
    }
  }
  W1P[idx] = __half_as_ushort(__float2half_rn(v));
}

// epi4[node][16 uints] W2 pairs laid for [g][r]; b2t[node]
__global__ void prep_epi4(const float* __restrict__ W2, const float* __restrict__ b2,
                          uint_t* __restrict__ epi4, float* __restrict__ b2t) {
  int idx = blockIdx.x * 256 + threadIdx.x;
  if (idx < NN * 16) {
    int node = idx >> 4;
    int g = (idx >> 2) & 3;
    int r = idx & 3;
    int j0 = ((r & 2) << 3) + 4 * g + ((r & 1) << 1);
    uint_t lo = __half_as_ushort(__float2half_rn(W2[node * HH + j0]));
    uint_t hi = __half_as_ushort(__float2half_rn(W2[node * HH + j0 + 1]));
    epi4[idx] = lo | (hi << 16);
  } else if (idx < NN * 16 + NN) {
    int node = idx - NN * 16;
    b2t[node] = b2[node];
  }
}

// ======================= superstep macro (textual, allocator-safe) ==========
#define SUPERSTEP_BODY(NSC)                                                    \
  {                                                                            \
    asm volatile("s_waitcnt vmcnt(0) lgkmcnt(0)" ::: "memory");                \
    __builtin_amdgcn_s_barrier();                                              \
    __builtin_amdgcn_sched_barrier(0);                                         \
    tsb ^= 32768;                                                              \
    xtb ^= 4096;                                                               \
    if (ss < 24) {                                                             \
      _Pragma("unroll")                                                        \
      for (int q = 0; q < 4; ++q)                                              \
        nn2[q] = __builtin_amdgcn_readfirstlane(ord[4 * (ss + 1) + q]);        \
      const int nC = ((4 * ss + 41) >> 5) << 1;                                \
      const int dset = tsb ^ 32768;                                            \
      {                                                                        \
        const int q2 = w >> 2, c2 = w & 3;                                     \
        const int nsel = SELQ(nn2, q2);                                        \
        const char* gb = (const char*)Wd + (size_t)nsel * 8192;                \
        char* lb = (char*)smem + dset + q2 * 8192;                             \
        if (c2 < nC) {                                                         \
          __builtin_amdgcn_global_load_lds(                                    \
              (const AS_GLOBAL void*)(gb + c2 * 1024 + (size_t)lane * 16),     \
              (AS_LDS void*)(lb + c2 * 1024), 16, 0, 0);                       \
        }                                                                      \
        if (c2 + 4 < nC) {                                                     \
          __builtin_amdgcn_global_load_lds(                                    \
              (const AS_GLOBAL void*)(gb + (c2 + 4) * 1024 + (size_t)lane * 16), \
              (AS_LDS void*)(lb + (c2 + 4) * 1024), 16, 0, 0);                 \
        }                                                                      \
      }                                                                        \
      const int xd = XS_OFF + (xtb ^ 4096);                                    \
      _Pragma("unroll")                                                        \
      for (int q = 0; q < 4; ++q) {                                            \
        if (w == q) {                                                          \
          const ushort_t* gx = xTh + (size_t)nn2[q] * BB + bx * 512 + lane * 8;\
          __builtin_amdgcn_global_load_lds((const AS_GLOBAL void*)gx,          \
              (AS_LDS void*)(smem + xd + q * 1024), 16, 0, 0);                 \
        }                                                                      \
      }                                                                        \
    }                                                                          \
    _Pragma("unroll")                                                          \
    for (int q = 0; q < 4; ++q) {                                              \
      const int st = 4 * ss + q + 2;                                           \
      const int node = nd[q];                                                  \
      const uint_t xw =                                                        \
          *(const uint_t*)(sp + XS_OFF + xtb + w * 64 + n16 * 4 + q * 1024);   \
      breg[0][0].x = (g == 0) ? (0x00003C00u | (xw << 16)) : breg[0][0].x;     \
      breg[1][0].x = (g == 0) ? (0x00003C00u | (xw & 0xFFFF0000u)) : breg[1][0].x; \
      float val0, val1;                                                        \
      if (node != di) {                                                        \
        const uint4 w4 = *(const uint4*)(sp + EPI4_OFF + node * 64 + g * 16);  \
        const float b2n = *(const float*)(sp + B2T_OFF + node * 4);            \
        const int tb = tsb + q * 8192;                                         \
        f32x4 acc0, acc1;                                                      \
        float p00, p01;                                                        \
        __builtin_amdgcn_s_setprio(1);                                         \
        _Pragma("unroll")                                                      \
        for (int s = 0; s < (NSC); ++s) {                                      \
          FU a, b0_, b1_;                                                      \
          a.u = *(const uint4*)(sp + tb + s * 2048 + vsw);                     \
          b0_.u = breg[0][s]; b1_.u = breg[1][s];                              \
          if (s == 0) {                                                        \
            acc0 = __builtin_amdgcn_mfma_f32_16x16x32_f16(a.h, b0_.h, zero4, 0, 0, 0); \
            acc1 = __builtin_amdgcn_mfma_f32_16x16x32_f16(a.h, b1_.h, zero4, 0, 0, 0); \
          } else {                                                             \
            acc0 = __builtin_amdgcn_mfma_f32_16x16x32_f16(a.h, b0_.h, acc0, 0, 0, 0); \
            acc1 = __builtin_amdgcn_mfma_f32_16x16x32_f16(a.h, b1_.h, acc1, 0, 0, 0); \
          }                                                                    \
        }                                                                      \
        __builtin_amdgcn_s_setprio(0);                                         \
        {                                                                      \
          PU w01, w23; w01.u = w4.x; w23.u = w4.y;                             \
          PU h01, h23;                                                         \
          h01.p = __builtin_amdgcn_cvt_pkrtz(acc0[0], acc0[1]);                \
          h23.p = __builtin_amdgcn_cvt_pkrtz(acc0[2], acc0[3]);                \
          h01.p = __builtin_elementwise_max(h01.p, h01.p * c001.p);            \
          h23.p = __builtin_elementwise_max(h23.p, h23.p * c001.p);            \
          float p = __builtin_amdgcn_fdot2(h01.h, w01.h, 0.f, false);          \
          p00 = __builtin_amdgcn_fdot2(h23.h, w23.h, p, false);                \
          h01.p = __builtin_amdgcn_cvt_pkrtz(acc1[0], acc1[1]);                \
          h23.p = __builtin_amdgcn_cvt_pkrtz(acc1[2], acc1[3]);                \
          h01.p = __builtin_elementwise_max(h01.p, h01.p * c001.p);            \
          h23.p = __builtin_elementwise_max(h23.p, h23.p * c001.p);            \
          p = __builtin_amdgcn_fdot2(h01.h, w01.h, 0.f, false);                \
          p01 = __builtin_amdgcn_fdot2(h23.h, w23.h, p, false);                \
        }                                                                      \
        __builtin_amdgcn_s_setprio(1);                                         \
        _Pragma("unroll")                                                      \
        for (int s = 0; s < (NSC); ++s) {                                      \
          FU a, b0_, b1_;                                                      \
          a.u = *(const uint4*)(sp + tb + s * 2048 + 1024 + vsw);              \
          b0_.u = breg[0][s]; b1_.u = breg[1][s];                              \
          if (s == 0) {                                                        \
            acc0 = __builtin_amdgcn_mfma_f32_16x16x32_f16(a.h, b0_.h, zero4, 0, 0, 0); \
            acc1 = __builtin_amdgcn_mfma_f32_16x16x32_f16(a.h, b1_.h, zero4, 0, 0, 0); \
          } else {                                                             \
            acc0 = __builtin_amdgcn_mfma_f32_16x16x32_f16(a.h, b0_.h, acc0, 0, 0, 0); \
            acc1 = __builtin_amdgcn_mfma_f32_16x16x32_f16(a.h, b1_.h, acc1, 0, 0, 0); \
          }                                                                    \
        }                                                                      \
        __builtin_amdgcn_s_setprio(0);                                         \
        {                                                                      \
          PU w45, w67; w45.u = w4.z; w67.u = w4.w;                             \
          PU h45, h67;                                                         \
          h45.p = __builtin_amdgcn_cvt_pkrtz(acc0[0], acc0[1]);                \
          h67.p = __builtin_amdgcn_cvt_pkrtz(acc0[2], acc0[3]);                \
          h45.p = __builtin_elementwise_max(h45.p, h45.p * c001.p);            \
          h67.p = __builtin_elementwise_max(h67.p, h67.p * c001.p);            \
          float p = __builtin_amdgcn_fdot2(h45.h, w45.h, p00, false);          \
          p = __builtin_amdgcn_fdot2(h67.h, w67.h, p, false);                  \
          p += __shfl_xor(p, 16, 64);                                          \
          p += __shfl_xor(p, 32, 64);                                          \
          val0 = p + b2n;                                                      \
          h45.p = __builtin_amdgcn_cvt_pkrtz(acc1[0], acc1[1]);                \
          h67.p = __builtin_amdgcn_cvt_pkrtz(acc1[2], acc1[3]);                \
          h45.p = __builtin_elementwise_max(h45.p, h45.p * c001.p);            \
          h67.p = __builtin_elementwise_max(h67.p, h67.p * c001.p);            \
          p = __builtin_amdgcn_fdot2(h45.h, w45.h, p01, false);                \
          p = __builtin_amdgcn_fdot2(h67.h, w67.h, p, false);                  \
          p += __shfl_xor(p, 16, 64);                                          \
          p += __shfl_xor(p, 32, 64);                                          \
          val1 = p + b2n;                                                      \
        }                                                                      \
      } else {                                                                 \
        val0 = __half2float(__ushort_as_half((ushort_t)(xw & 0xFFFFu)));       \
        val1 = __half2float(__ushort_as_half((ushort_t)(xw >> 16)));           \
      }                                                                        \
      const int sn = st >> 5;                                                  \
      const int en2 = (st >> 1) & 3;                                           \
      const int gn = (st >> 3) & 3;                                            \
      const int hin = st & 1;                                                  \
      const bool own = (g == gn);                                              \
      const uint_t hv0 = (uint_t)__half_as_ushort(__float2half_rn(val0));      \
      const uint_t hv1 = (uint_t)__half_as_ushort(__float2half_rn(val1));      \
      _Pragma("unroll")                                                        \
      for (int S = 0; S < (NSC); ++S) {                                        \
        if (S != sn) continue;                                                 \
        _Pragma("unroll")                                                      \
        for (int nt = 0; nt < 2; ++nt) {                                       \
          uint4& Bq = breg[nt][S];                                             \
          uint_t hvn = nt ? hv1 : hv0;                                         \
          if (en2 == 0) {                                                      \
            uint_t old = Bq.x;                                                 \
            uint_t nw = hin ? ((old & 0x0000FFFFu) | (hvn << 16))              \
                            : ((old & 0xFFFF0000u) | hvn);                     \
            Bq.x = own ? nw : old;                                             \
          } else if (en2 == 1) {                                               \
            uint_t old = Bq.y;                                                 \
            uint_t nw = hin ? ((old & 0x0000FFFFu) | (hvn << 16))              \
                            : ((old & 0xFFFF0000u) | hvn);                     \
            Bq.y = own ? nw : old;                                             \
          } else if (en2 == 2) {                                               \
            uint_t old = Bq.z;                                                 \
            uint_t nw = hin ? ((old & 0x0000FFFFu) | (hvn << 16))              \
                            : ((old & 0xFFFF0000u) | hvn);                     \
            Bq.z = own ? nw : old;                                             \
          } else {                                                             \
            uint_t old = Bq.w;                                                 \
            uint_t nw = hin ? ((old & 0x0000FFFFu) | (hvn << 16))              \
                            : ((old & 0xFFFF0000u) | hvn);                     \
            Bq.w = own ? nw : old;                                             \
          }                                                                    \
        }                                                                      \
      }                                                                        \
    }                                                                          \
    _Pragma("unroll")                                                          \
    for (int q = 0; q < 4; ++q) nd[q] = nn2[q];                                \
  }

// ======================= main =======================
__global__ __launch_bounds__(TPB, 8) void dag_mfma_ks(
    const ushort_t* __restrict__ xTh,  // [N][B] fp16 paired
    const int* __restrict__ order,     // [D][N]
    const int* __restrict__ do_idx_p,  // [1]
    const ushort_t* __restrict__ W1P,  // [D][N][4096] fp16 slice-major swizzled
    const uint_t* __restrict__ epi4_g, // [N][16]
    const float* __restrict__ b2t_g,   // [N]
    float* __restrict__ out)           // [D][B][N]
{
  __shared__ __align__(16) char smem[SMEM_BYTES];
  const char* sp = (const char*)smem;

  const int d = blockIdx.y;
  const int bx = blockIdx.x;
  const int tid = threadIdx.x;
  const int w = tid >> 6;
  const int lane = tid & 63;
  const int g = lane >> 4;
  const int n16 = lane & 15;
  const int di = __builtin_amdgcn_readfirstlane(do_idx_p[0]);
  const int* ord = order + d * NN;

  // preloads: epi4 (400 uint4), b2t (100 f32), inv table (100 u16)
  {
    const uint4* s4 = (const uint4*)epi4_g;
    uint4* d4 = (uint4*)(smem + EPI4_OFF);
    for (int i = tid; i < 400; i += TPB) d4[i] = s4[i];
    if (tid < NN) {
      ((float*)(smem + B2T_OFF))[tid] = b2t_g[tid];
      ((ushort_t*)(smem + INV_OFF))[ord[tid]] = (ushort_t)(tid + 2);
    }
  }

  const ushort_t* Wd = W1P + (size_t)d * NN * 4096;
  const int vsw = n16 * 64 + ((g ^ (n16 & 3)) << 4);
  int tsb = 32768;
  int xtb = 4096;

  int nd[4], nn2[4];
#pragma unroll
  for (int q = 0; q < 4; ++q) { nd[q] = __builtin_amdgcn_readfirstlane(ord[q]); nn2[q] = nd[q]; }
  {
    const int q = w >> 2, c = w & 3;   // ss=0: NS=1 -> 2 chunks
    const int nsel = SELQ(nd, q);
    const char* gb = (const char*)Wd + (size_t)nsel * 8192;
    if (c < 2) {
      __builtin_amdgcn_global_load_lds(
          (const AS_GLOBAL void*)(gb + c * 1024 + (size_t)lane * 16),
          (AS_LDS void*)(smem + q * 8192 + c * 1024), 16, 0, 0);
    }
  }
#pragma unroll
  for (int q = 0; q < 4; ++q) {
    if (w == q) {
      const ushort_t* gx = xTh + (size_t)nd[q] * BB + bx * 512 + lane * 8;
      __builtin_amdgcn_global_load_lds((const AS_GLOBAL void*)gx,
          (AS_LDS void*)(smem + XS_OFF + q * 1024), 16, 0, 0);
    }
  }

  uint4 breg[2][4];
#pragma unroll
  for (int nt = 0; nt < 2; ++nt) {
#pragma unroll
    for (int S = 0; S < 4; ++S) breg[nt][S] = make_uint4(0u, 0u, 0u, 0u);
    breg[nt][0].x = (g == 0) ? 0x00003C00u : 0u;
  }

  const f32x4 zero4 = {0.f, 0.f, 0.f, 0.f};
  PU c001; c001.u = 0x211F211Fu;   // fp16 0.01 x2

  // four sequential loops, NS compile-time per loop (monotone schedule)
#pragma unroll 1
  for (int ss = 0; ss < 7; ++ss) SUPERSTEP_BODY(1)
#pragma unroll 1
  for (int ss = 7; ss < 15; ++ss) SUPERSTEP_BODY(2)
#pragma unroll 1
  for (int ss = 15; ss < 23; ++ss) SUPERSTEP_BODY(3)
#pragma unroll 1
  for (int ss = 23; ss < 25; ++ss) SUPERSTEP_BODY(4)

  // ---- output: per-wave 32-row LDS transpose chunks; inv maps node->slot
  ushort_t* tbuf = (ushort_t*)smem;   // 32*132 halfs
  const ushort_t* invp = (const ushort_t*)(smem + INV_OFF);
#pragma unroll 1
  for (int c = 0; c < 16; ++c) {
    __syncthreads();
    if (w == c) {
#pragma unroll
      for (int nt = 0; nt < 2; ++nt) {
        int r = nt * 16 + n16;
#pragma unroll
        for (int S = 0; S < 4; ++S) {
          int k = 32 * S + 8 * g;
          *(uint2*)&tbuf[r * 132 + k] = make_uint2(breg[nt][S].x, breg[nt][S].y);
          *(uint2*)&tbuf[r * 132 + k + 4] = make_uint2(breg[nt][S].z, breg[nt][S].w);
        }
      }
    }
    __syncthreads();
    const size_t obase = ((size_t)d * BB + bx * 512 + c * 32) * NN;
    for (int idx = tid; idx < 32 * NN; idx += TPB) {
      int rl = idx / NN;
      int col = idx - rl * NN;
      int slot = invp[col];
      out[obase + idx] = __half2float(__ushort_as_half(tbuf[rl * 132 + slot]));
    }
  }
}

// ======================= launch =======================
extern "C" void kernel_launch(void* const* d_in, const int* in_sizes, int n_in,
                              void* d_out, int out_size, void* d_ws, size_t ws_size,
                              hipStream_t stream) {
  const float* x     = (const float*)d_in[0];
  const float* A     = (const float*)d_in[1];
  const int* order   = (const int*)d_in[2];
  const int* do_idx  = (const int*)d_in[3];
  const float* W1    = (const float*)d_in[4];
  const float* b1    = (const float*)d_in[5];
  const float* W2    = (const float*)d_in[6];
  const float* b2    = (const float*)d_in[7];
  float* out = (float*)d_out;

  char* ws = (char*)d_ws;
  const size_t XTH_B = (size_t)BB * NN * 2;         // 1,638,400
  const size_t W1P_B = (size_t)DD * NN * 4096 * 2;  // 26,214,400
  ushort_t* xTh  = (ushort_t*)ws;
  ushort_t* W1P  = (ushort_t*)(ws + XTH_B);
  uint_t* epi4   = (uint_t*)(ws + XTH_B + W1P_B);           // 6,400 B
  float* b2t     = (float*)(ws + XTH_B + W1P_B + 6400);     // 400 B

  hipLaunchKernelGGL(prep_xth, dim3((BB * NN) / 256), dim3(256), 0, stream, x, xTh);
  hipLaunchKernelGGL(prep_w1p, dim3((DD * NN * 4096) / 256), dim3(256), 0, stream,
                     A, W1, b1, order, W1P);
  hipLaunchKernelGGL(prep_epi4, dim3((NN * 16 + NN + 255) / 256), dim3(256), 0, stream,
                     W2, b2, epi4, b2t);
  hipLaunchKernelGGL(dag_mfma_ks, dim3(BB / 512, DD), dim3(TPB), 0, stream,
                     xTh, order, do_idx, W1P, epi4, b2t, out);
}